// Round 7
// baseline (131.511 us; speedup 1.0000x reference)
//
#include <hip/hip_runtime.h>
#include <math.h>

typedef _Float16 f16;
typedef f16   f16x8    __attribute__((ext_vector_type(8)));
typedef float floatx4  __attribute__((ext_vector_type(4)));
typedef float floatx16 __attribute__((ext_vector_type(16)));

#define LOG2E 1.44269504088896340736f

// Problem constants
#define B_SZ  2048
#define DIN   64
#define DOUT  64
#define NH    32

#define NIG   2                 // i-groups -> grid 4096 blocks = 8192 waves = 8/SIMD (one fill)
#define IGW   (DIN / NIG)       // 32 i per block

// Images:
//  w1img f16 [i][o][lane(64)][j(8)]: A-frag mfma_32x32x16, m=h=lane&31,
//        k=(lane>>5)*8+j; lanes 32..63 ZERO (k=8..15 dead). Scaled by -log2e;
//        j==7 holds B1*(-log2e) (bias via constant-1 feature).
//  fimg  f16 [i][btp(64)][lane(64)][j(8)]: B-frag, n=b=lane&31; j==7 = 1.0.
//        lanes 32..63 NEVER READ meaningfully (A is zero there) -> not written.
//  w2q   f32 [i][o][q(4)][p(2)][r(4)] = W2[i,o,h=q*8+p*4+r] * (-1/log2e)
//  b2sum f32 [64]: column sums of B2.
#define W1IMG_ELEMS ((size_t)DIN * DOUT * 64 * 8)   // 4 MB
#define FIMG_ELEMS  ((size_t)DIN * 64 * 64 * 8)     // 4 MB
#define W2Q_ELEMS   ((size_t)DIN * DOUT * NH)       // 512 KB

// ---------------------------------------------------------------------------
// prep: bid [0,256)   w1img — 16 (i,o) pairs/block, coalesced via LDS
//       bid [256,320) fimg  — 1 btp/block, coalesced x via LDS transpose
//       bid [320,832) w2q
//       bid 832       b2sum
// ---------------------------------------------------------------------------
__global__ __launch_bounds__(256) void prep_kernel(
        const float* __restrict__ W1, const float* __restrict__ B1,
        const float* __restrict__ W2, const float* __restrict__ B2,
        const float* __restrict__ x,
        f16* __restrict__ w1img, f16* __restrict__ fimg,
        float* __restrict__ w2q, float* __restrict__ b2sum) {
    const int bid = blockIdx.x, tid = threadIdx.x;
    if (bid < 256) {
        __shared__ float l1[16 * 225];   // 16 pairs x 224 (+1 pad)
        __shared__ float lb[16 * 32];
        const int base = bid * 16;       // pair = i*64+o
        for (int g = tid; g < 3584; g += 256) {
            int pair = g / 224, r = g % 224;
            l1[pair * 225 + r] = W1[(size_t)base * 224 + g];
        }
        for (int g = tid; g < 512; g += 256) lb[g] = B1[(size_t)base * 32 + g];
        __syncthreads();
        for (int g = tid; g < 1024; g += 256) {
            int pair = g >> 6, lane = g & 63;
            f16x8 v = {};
            if (lane < 32) {
#pragma unroll
                for (int j = 0; j < 7; ++j)
                    v[j] = (f16)(l1[pair * 225 + lane * 7 + j] * (-LOG2E));
                v[7] = (f16)(lb[pair * 32 + lane] * (-LOG2E));
            }
            *(f16x8*)(w1img + (size_t)bid * 8192 + (size_t)g * 8) = v;
        }
    } else if (bid < 320) {
        __shared__ float ls[32 * 65];
        const int btp = bid - 256;
        for (int g = tid; g < 2048; g += 256) {
            int bb = g >> 6, i = g & 63;
            ls[bb * 65 + i] = x[(size_t)(btp * 32 + bb) * 64 + i];
        }
        __syncthreads();
        for (int g = tid; g < 2048; g += 256) {
            int bb = g & 31, i = g >> 5;
            float xv = ls[bb * 65 + i];
            float s1, c1;
            __sincosf(xv, &s1, &c1);
            float s2 = 2.0f * s1 * c1, c2 = 1.0f - 2.0f * s1 * s1;
            float s4 = 2.0f * s2 * c2, c4 = 1.0f - 2.0f * s2 * s2;
            f16x8 v;
            v[0] = (f16)xv; v[1] = (f16)s1; v[2] = (f16)s2; v[3] = (f16)s4;
            v[4] = (f16)c1; v[5] = (f16)c2; v[6] = (f16)c4; v[7] = (f16)1.0f;
            *(f16x8*)(fimg + ((size_t)(i * 64 + btp) * 64 + bb) * 8) = v;
        }
    } else if (bid < 832) {
        int e = (bid - 320) * 256 + tid;     // < 131072
        int r = e & 3, p = (e >> 2) & 1, q = (e >> 3) & 3;
        int o = (e >> 5) & 63, i = e >> 11;
        int h = q * 8 + p * 4 + r;
        w2q[e] = W2[(size_t)(i * 64 + o) * 32 + h] * (-1.0f / LOG2E);
    } else if (tid < 64) {
        float s = 0.0f;
        for (int i = 0; i < 64; ++i) s += B2[i * 64 + tid];
        b2sum[tid] = s;
    }
}

// ---------------------------------------------------------------------------
// main: grid = 2 ig x 32 og x 64 btp = 4096 blocks, block 128 (2 waves);
// wave w -> o = og*2+w; 32 i per block. Per i: ONE mfma_32x32x16 ->
// C[h(32) x b(32)]. silu+w2 via 4-way SHARED-RCP groups (exact algebra):
//   sum_r p_r/(1+u_r) = N/D, one v_rcp per 4 elements (trans 32->20 /iter).
// a/b software-prefetched 1 ahead; w2 loaded in-iter (compiler hoists).
// ---------------------------------------------------------------------------
__global__ __launch_bounds__(128, 4) void main_kernel(
        const f16* __restrict__ w1img, const f16* __restrict__ fimg,
        const float* __restrict__ w2q, float* __restrict__ partials) {
    const int tid  = threadIdx.x;
    const int lane = tid & 63;
    const int wv   = tid >> 6;
    const int btp  = blockIdx.x & 63;
    const int og   = (blockIdx.x >> 6) & 31;
    const int ig   = blockIdx.x >> 11;
    const int o    = __builtin_amdgcn_readfirstlane(og * 2 + wv);
    const int p    = lane >> 5;

    const size_t ibase = (size_t)ig * IGW;
    const f16*   ap = w1img + ibase * 32768 + ((size_t)o * 64 + lane) * 8;
    const f16*   bp = fimg  + ibase * 32768 + ((size_t)btp * 64 + lane) * 8;
    const float* wp = w2q   + ibase * 2048  + (size_t)o * 32 + p * 4;

    f16x8 a = *(const f16x8*)ap;
    f16x8 b = *(const f16x8*)bp;

    float phi = 0.0f;
    const floatx16 zeroC = {};

#pragma unroll 1
    for (int ii = 0; ii < IGW; ++ii) {
        const f16x8 ca = a, cb = b;

        // prefetch ii+1 (last iter overruns into the next ws region — finite
        // garbage, never consumed)
        const size_t i1 = (size_t)(ii + 1);
        a = *(const f16x8*)(ap + i1 * 32768);
        b = *(const f16x8*)(bp + i1 * 32768);

        const floatx4 w0 = *(const floatx4*)(wp + (size_t)ii * 2048);
        const floatx4 w1 = *(const floatx4*)(wp + (size_t)ii * 2048 + 8);
        const floatx4 w2 = *(const floatx4*)(wp + (size_t)ii * 2048 + 16);
        const floatx4 w3 = *(const floatx4*)(wp + (size_t)ii * 2048 + 24);

        floatx16 C = __builtin_amdgcn_mfma_f32_32x32x16_f16(ca, cb, zeroC, 0, 0, 0);

        // 4 groups of 4 elements; per group ONE rcp:
        //   sum_r p_r/v_r = (n01*d23 + n23*d01) / (d01*d23)
#pragma unroll
        for (int q = 0; q < 4; ++q) {
            const floatx4 wq = (q == 0) ? w0 : (q == 1) ? w1 : (q == 2) ? w2 : w3;
            float t0 = C[4 * q + 0], t1 = C[4 * q + 1];
            float t2 = C[4 * q + 2], t3 = C[4 * q + 3];
            float u0 = __builtin_amdgcn_exp2f(t0);
            float u1 = __builtin_amdgcn_exp2f(t1);
            float u2 = __builtin_amdgcn_exp2f(t2);
            float u3 = __builtin_amdgcn_exp2f(t3);
            float v0 = 1.0f + u0, v1 = 1.0f + u1, v2 = 1.0f + u2, v3 = 1.0f + u3;
            float p0 = t0 * wq[0], p1 = t1 * wq[1], p2 = t2 * wq[2], p3 = t3 * wq[3];
            float d01 = v0 * v1, d23 = v2 * v3;
            float n01 = __builtin_fmaf(p1, v0, p0 * v1);
            float n23 = __builtin_fmaf(p3, v2, p2 * v3);
            float n   = __builtin_fmaf(n23, d01, n01 * d23);
            float D   = d01 * d23;
            phi = __builtin_fmaf(n, __builtin_amdgcn_rcpf(D), phi);
        }
    }

    // combine the two row-halves (lane and lane^32 share the same column)
    phi += __shfl_xor(phi, 32, 64);

    if (lane < 32) {
        partials[((size_t)ig * B_SZ + btp * 32 + lane) * 64 + o] = phi;
    }
}

// ---------------------------------------------------------------------------
// reduce: out[b,o] = sum_ig partials[ig][b][o] + b2sum[o]
// ---------------------------------------------------------------------------
__global__ __launch_bounds__(256) void reduce_kernel(
        const float* __restrict__ partials, const float* __restrict__ b2sum,
        float* __restrict__ out) {
    int t = blockIdx.x * 256 + threadIdx.x;    // < 32768 float4s
    floatx4 s = *(const floatx4*)(b2sum + ((t * 4) & 63));
#pragma unroll
    for (int gg = 0; gg < NIG; ++gg) {
        floatx4 v = *(const floatx4*)(partials + (size_t)gg * (B_SZ * DOUT) + t * 4);
        s += v;
    }
    *(floatx4*)(out + (size_t)t * 4) = s;
}

extern "C" void kernel_launch(void* const* d_in, const int* in_sizes, int n_in,
                              void* d_out, int out_size, void* d_ws, size_t ws_size,
                              hipStream_t stream) {
    const float* x  = (const float*)d_in[0];
    const float* W1 = (const float*)d_in[1];
    const float* W2 = (const float*)d_in[2];
    const float* B1 = (const float*)d_in[3];
    const float* B2 = (const float*)d_in[4];
    float* out = (float*)d_out;

    // ws: w1img (4MB) | fimg (4MB) | w2q (512KB) | b2sum | partials (1MB) | pad
    f16*   w1img    = (f16*)d_ws;
    f16*   fimg     = w1img + W1IMG_ELEMS;
    float* w2q      = (float*)(fimg + FIMG_ELEMS);
    float* b2sum    = w2q + W2Q_ELEMS;
    float* partials = b2sum + 64;

    prep_kernel<<<833, 256, 0, stream>>>(W1, B1, W2, B2, x, w1img, fimg, w2q, b2sum);
    main_kernel<<<NIG * 32 * 64, 128, 0, stream>>>(w1img, fimg, w2q, partials);
    reduce_kernel<<<(B_SZ * DOUT) / 1024, 256, 0, stream>>>(partials, b2sum, out);
}

// Round 8
// 129.778 us; speedup vs baseline: 1.0134x; 1.0134x over previous
//
#include <hip/hip_runtime.h>
#include <math.h>

typedef _Float16 f16;
typedef f16   f16x8    __attribute__((ext_vector_type(8)));
typedef float floatx4  __attribute__((ext_vector_type(4)));
typedef float floatx16 __attribute__((ext_vector_type(16)));

#define LOG2E 1.44269504088896340736f
#define LN2   0.69314718055994530942f

// Problem constants
#define B_SZ  2048
#define DIN   64
#define DOUT  64
#define NH    32

#define NIG   4                 // i-groups: 8192 blocks (2 residency fills — best measured occ)
#define IGW   (DIN / NIG)       // 16 i per block

// Images:
//  w1img f16 [i][o][lane(64)][j(8)]: A-frag mfma_32x32x16, m=h=lane&31,
//        k=(lane>>5)*8+j; lanes 32..63 ZERO (k=8..15 dead). Scaled by -log2e;
//        j==7 holds B1*(-log2e) (bias via constant-1 feature).
//  fimg  f16 [i][btp(64)][lane(64)][j(8)]: B-frag, n=b=lane&31; j==7 = 1.0.
//        lanes 32..63 never consumed (A zero there) -> not written.
//  W2 is read RAW in main (its [i][o][h] layout already matches the C-layout
//  gather: float4 at +p*4+q*8); the -ln2 factor is applied once per wave.
#define W1IMG_ELEMS ((size_t)DIN * DOUT * 64 * 8)   // 4 MB
#define FIMG_ELEMS  ((size_t)DIN * 64 * 64 * 8)     // 4 MB

// ---------------------------------------------------------------------------
// prep: bid [0,256)   w1img — 16 (i,o) pairs/block, coalesced via LDS
//       bid [256,320) fimg  — 1 btp/block, coalesced x via LDS transpose
//       bid [320,832) out[b,o] = sum_i B2[i,o]  (B2 colsum broadcast; main
//                     then ATOMICALLY adds its partial phis — no reduce kernel)
// ---------------------------------------------------------------------------
__global__ __launch_bounds__(256) void prep_kernel(
        const float* __restrict__ W1, const float* __restrict__ B1,
        const float* __restrict__ B2, const float* __restrict__ x,
        f16* __restrict__ w1img, f16* __restrict__ fimg,
        float* __restrict__ out) {
    const int bid = blockIdx.x, tid = threadIdx.x;
    if (bid < 256) {
        __shared__ float l1[16 * 225];   // 16 pairs x 224 (+1 pad)
        __shared__ float lb[16 * 32];
        const int base = bid * 16;       // pair = i*64+o
        for (int g = tid; g < 3584; g += 256) {
            int pair = g / 224, r = g % 224;
            l1[pair * 225 + r] = W1[(size_t)base * 224 + g];
        }
        for (int g = tid; g < 512; g += 256) lb[g] = B1[(size_t)base * 32 + g];
        __syncthreads();
        for (int g = tid; g < 1024; g += 256) {
            int pair = g >> 6, lane = g & 63;
            f16x8 v = {};
            if (lane < 32) {
#pragma unroll
                for (int j = 0; j < 7; ++j)
                    v[j] = (f16)(l1[pair * 225 + lane * 7 + j] * (-LOG2E));
                v[7] = (f16)(lb[pair * 32 + lane] * (-LOG2E));
            }
            *(f16x8*)(w1img + (size_t)bid * 8192 + (size_t)g * 8) = v;
        }
    } else if (bid < 320) {
        __shared__ float ls[32 * 65];
        const int btp = bid - 256;
        for (int g = tid; g < 2048; g += 256) {
            int bb = g >> 6, i = g & 63;
            ls[bb * 65 + i] = x[(size_t)(btp * 32 + bb) * 64 + i];
        }
        __syncthreads();
        for (int g = tid; g < 2048; g += 256) {
            int bb = g & 31, i = g >> 5;
            float xv = ls[bb * 65 + i];
            float s1, c1;
            __sincosf(xv, &s1, &c1);
            float s2 = 2.0f * s1 * c1, c2 = 1.0f - 2.0f * s1 * s1;
            float s4 = 2.0f * s2 * c2, c4 = 1.0f - 2.0f * s2 * s2;
            f16x8 v;
            v[0] = (f16)xv; v[1] = (f16)s1; v[2] = (f16)s2; v[3] = (f16)s4;
            v[4] = (f16)c1; v[5] = (f16)c2; v[6] = (f16)c4; v[7] = (f16)1.0f;
            *(f16x8*)(fimg + ((size_t)(i * 64 + btp) * 64 + bb) * 8) = v;
        }
    } else {
        int e = (bid - 320) * 256 + tid;  // < 131072; b = e>>6, o = e&63
        int o = e & 63;
        float s = 0.0f;
#pragma unroll 8
        for (int i = 0; i < 64; ++i) s += B2[i * 64 + o];   // 16 KB, L2-hot
        out[e] = s;
    }
}

// ---------------------------------------------------------------------------
// main: grid = 4 ig x 32 og x 64 btp = 8192 blocks, block 128 (2 waves);
// wave w -> o = og*2+w; 16 i per block. Per i: ONE mfma_32x32x16 ->
// C[h(32) x b(32)] (real K=8, zeros baked in -> unconditional loads).
// silu in-register: weights pre-scaled by -log2e so t = -a*log2e,
//   sg = rcp(1+2^t), phi_raw += t*w2raw*sg;  final = -ln2*phi_raw
// (W2 read RAW: its [i][o][h] layout natively serves the C-layout float4
// gather at +p*4+q*8). Result atomically added into pre-initialized out.
// ---------------------------------------------------------------------------
__global__ __launch_bounds__(128, 8) void main_kernel(
        const f16* __restrict__ w1img, const f16* __restrict__ fimg,
        const float* __restrict__ W2, float* __restrict__ out) {
    const int tid  = threadIdx.x;
    const int lane = tid & 63;
    const int wv   = tid >> 6;
    const int btp  = blockIdx.x & 63;
    const int og   = (blockIdx.x >> 6) & 31;
    const int ig   = blockIdx.x >> 11;
    const int o    = __builtin_amdgcn_readfirstlane(og * 2 + wv);
    const int p    = lane >> 5;

    const size_t ibase = (size_t)ig * IGW;
    const f16*   ap = w1img + ibase * 32768 + ((size_t)o * 64 + lane) * 8;
    const f16*   bp = fimg  + ibase * 32768 + ((size_t)btp * 64 + lane) * 8;
    const float* wp = W2    + ibase * 2048  + (size_t)o * 32 + p * 4;

    f16x8 a = *(const f16x8*)ap;
    f16x8 b = *(const f16x8*)bp;

    float phi = 0.0f;
    const floatx16 zeroC = {};

#pragma unroll 1
    for (int ii = 0; ii < IGW; ++ii) {
        const f16x8 ca = a, cb = b;

        // prefetch ii+1 (last iter overruns into the adjacent ws region /
        // end pad — finite garbage, never consumed)
        const size_t i1 = (size_t)(ii + 1);
        a = *(const f16x8*)(ap + i1 * 32768);
        b = *(const f16x8*)(bp + i1 * 32768);

        const floatx4 w0 = *(const floatx4*)(wp + (size_t)ii * 2048);       // q=0: h=p*4+r
        const floatx4 w1 = *(const floatx4*)(wp + (size_t)ii * 2048 + 8);   // q=1
        const floatx4 w2 = *(const floatx4*)(wp + (size_t)ii * 2048 + 16);  // q=2
        const floatx4 w3 = *(const floatx4*)(wp + (size_t)ii * 2048 + 24);  // q=3

        floatx16 C = __builtin_amdgcn_mfma_f32_32x32x16_f16(ca, cb, zeroC, 0, 0, 0);

#pragma unroll
        for (int r = 0; r < 4; ++r) {
            float av, e2, sg;
            av = C[0 + r];  e2 = __builtin_amdgcn_exp2f(av);
            sg = __builtin_amdgcn_rcpf(1.0f + e2);
            phi = __builtin_fmaf(av * w0[r], sg, phi);
            av = C[4 + r];  e2 = __builtin_amdgcn_exp2f(av);
            sg = __builtin_amdgcn_rcpf(1.0f + e2);
            phi = __builtin_fmaf(av * w1[r], sg, phi);
            av = C[8 + r];  e2 = __builtin_amdgcn_exp2f(av);
            sg = __builtin_amdgcn_rcpf(1.0f + e2);
            phi = __builtin_fmaf(av * w2[r], sg, phi);
            av = C[12 + r]; e2 = __builtin_amdgcn_exp2f(av);
            sg = __builtin_amdgcn_rcpf(1.0f + e2);
            phi = __builtin_fmaf(av * w3[r], sg, phi);
        }
    }

    // combine the two row-halves (lane and lane^32 share the same column),
    // apply the deferred -ln2 (t = -a*log2e and raw W2)
    phi += __shfl_xor(phi, 32, 64);
    phi *= -LN2;

    if (lane < 32) {
        atomicAdd(&out[(size_t)(btp * 32 + lane) * 64 + o], phi);
    }
}

extern "C" void kernel_launch(void* const* d_in, const int* in_sizes, int n_in,
                              void* d_out, int out_size, void* d_ws, size_t ws_size,
                              hipStream_t stream) {
    const float* x  = (const float*)d_in[0];
    const float* W1 = (const float*)d_in[1];
    const float* W2 = (const float*)d_in[2];
    const float* B1 = (const float*)d_in[3];
    const float* B2 = (const float*)d_in[4];
    float* out = (float*)d_out;

    // ws: w1img (4MB) | fimg (4MB) | 64KB pad for last-iter prefetch overrun
    f16* w1img = (f16*)d_ws;
    f16* fimg  = w1img + W1IMG_ELEMS;

    prep_kernel<<<832, 256, 0, stream>>>(W1, B1, B2, x, w1img, fimg, out);
    main_kernel<<<NIG * 32 * 64, 128, 0, stream>>>(w1img, fimg, W2, out);
}